// Round 14
// baseline (317.798 us; speedup 1.0000x reference)
//
#include <hip/hip_runtime.h>
#include <hip/hip_bf16.h>
#include <math.h>

constexpr int DM = 1024;    // d_model
constexpr int NH = 16;      // heads
constexpr int DK = 64;      // head dim
constexpr int SQ = 2048;    // seq len
constexpr int BB = 2;       // batch
constexpr int MR = BB * SQ; // 4096 rows

typedef short bf16x8 __attribute__((ext_vector_type(8)));
typedef float f32x4 __attribute__((ext_vector_type(4)));
typedef float f32x16 __attribute__((ext_vector_type(16)));

__device__ inline unsigned short f2bf(float f) {
  unsigned u = __float_as_uint(f);
  unsigned r = (u + 0x7fffu + ((u >> 16) & 1u)) >> 16;  // RNE
  return (unsigned short)r;
}

// XOR swizzle for [R][64] bf16 LDS tiles. f(r) xors the 16B-granule index.
__device__ inline int fswz(int r) { return (r & 7) ^ ((r >> 3) & 7); }
__device__ inline int swz(int r, int c) {
  return r * 64 + ((((c >> 3) ^ fswz(r)) & 7) << 3) + (c & 7);
}
// [64][128] V^T tile: 16 granules/row, xor low 3 bits of granule index.
__device__ inline int vslot(int d, int g) { return (g & 8) | ((g ^ fswz(d)) & 7); }

// -------- cast f32 -> bf16, 8 elems/thread --------
__global__ __launch_bounds__(256)
void cast_kernel(const float* __restrict__ in, unsigned short* __restrict__ out, int n8) {
  int i = blockIdx.x * 256 + threadIdx.x;
  if (i >= n8) return;
  float4 a = *(const float4*)&in[(size_t)i * 8];
  float4 b = *(const float4*)&in[(size_t)i * 8 + 4];
  ushort4 lo = {f2bf(a.x), f2bf(a.y), f2bf(a.z), f2bf(a.w)};
  ushort4 hi = {f2bf(b.x), f2bf(b.y), f2bf(b.z), f2bf(b.w)};
  *(ushort4*)&out[(size_t)i * 8] = lo;
  *(ushort4*)&out[(size_t)i * 8 + 4] = hi;
}

// -------- cast+transpose: W[K][N] f32 -> Wt[N][K] bf16 (32x32 tiles) --------
__global__ __launch_bounds__(256)
void transpose_cast_kernel(const float* __restrict__ W, unsigned short* __restrict__ Wt) {
  __shared__ float tl[32][33];
  const int tx = threadIdx.x & 31, ty = threadIdx.x >> 5;  // 32 x 8
  const int x0 = blockIdx.x * 32, y0 = blockIdx.y * 32;    // x0: n, y0: k
  #pragma unroll
  for (int i = 0; i < 4; ++i)
    tl[ty + i * 8][tx] = W[(size_t)(y0 + ty + i * 8) * DM + x0 + tx];
  __syncthreads();
  #pragma unroll
  for (int i = 0; i < 4; ++i)
    Wt[(size_t)(x0 + ty + i * 8) * DM + y0 + tx] = f2bf(tl[tx][ty + i * 8]);
}

// -------- concat bias [bq|bk|bv] -> cb[3072] --------
__global__ __launch_bounds__(256)
void concat_bias(const float* __restrict__ bq, const float* __restrict__ bk,
                 const float* __restrict__ bv, float* __restrict__ cb) {
  int i = blockIdx.x * 256 + threadIdx.x;
  if (i < 1024) cb[i] = bq[i];
  else if (i < 2048) cb[i] = bk[i - 1024];
  else if (i < 3072) cb[i] = bv[i - 2048];
}

// -------- V transpose: [B,H,S,DK] -> [B,H,DK,S], 64x64 bf16 tiles --------
__global__ __launch_bounds__(256)
void transpose_v(const unsigned short* __restrict__ V, unsigned short* __restrict__ Vt) {
  __shared__ unsigned short tl[64 * 64];
  const int t = threadIdx.x;
  const int s0 = blockIdx.x * 64, bh = blockIdx.y;
  const unsigned short* src = V + (size_t)bh * SQ * DK;
  unsigned short* dst = Vt + (size_t)bh * DK * SQ;
  #pragma unroll
  for (int i = 0; i < 2; ++i) {
    int g = t + i * 256, r = g >> 3, cg = g & 7;
    uint4 v = *(const uint4*)&src[(size_t)(s0 + r) * DK + cg * 8];
    *(uint4*)&tl[r * 64 + (((cg ^ fswz(r)) & 7) << 3)] = v;
  }
  __syncthreads();
  #pragma unroll
  for (int i = 0; i < 2; ++i) {
    int g = t + i * 256, d = g >> 3, cs = g & 7;
    uint4 o;
    unsigned short* op = (unsigned short*)&o;
    #pragma unroll
    for (int e = 0; e < 8; ++e)
      op[e] = tl[swz(cs * 8 + e, d)];
    *(uint4*)&dst[(size_t)d * SQ + s0 + cs * 8] = o;
  }
}

// -------- fused QKV GEMM: [4096,1024] x Wt3[3072,1024]^T, 2-phase dbuf --------
__global__ __launch_bounds__(256)
void qkv_gemm(const unsigned short* __restrict__ A, const unsigned short* __restrict__ Wt3,
              const float* __restrict__ cbias, unsigned short* __restrict__ qkv)
{
  constexpr int K = DM;
  __shared__ unsigned short As[2][128 * 64];
  __shared__ unsigned short Bs[2][128 * 64];
  const int t = threadIdx.x;
  const int w = t >> 6, ln = t & 63;
  const int wr = w >> 1, wc = w & 1;
  const int rb = blockIdx.y * 128, cb = blockIdx.x * 128;

  f32x4 acc[4][4] = {};

  auto stage = [&](int buf, int k0) {
    #pragma unroll
    for (int j = 0; j < 4; ++j) {
      const int rows8 = (w * 4 + j) * 8;
      const int r = rows8 + (ln >> 3);
      const int gc = (((ln & 7) ^ fswz(r)) & 7) * 8;
      __builtin_amdgcn_global_load_lds(
          (const __attribute__((address_space(1))) void*)&A[(size_t)(rb + r) * K + k0 + gc],
          (__attribute__((address_space(3))) void*)&As[buf][rows8 * 64], 16, 0, 0);
      __builtin_amdgcn_global_load_lds(
          (const __attribute__((address_space(1))) void*)&Wt3[(size_t)(cb + r) * K + k0 + gc],
          (__attribute__((address_space(3))) void*)&Bs[buf][rows8 * 64], 16, 0, 0);
    }
  };

  stage(0, 0);
  asm volatile("s_waitcnt vmcnt(0)" ::: "memory");
  __builtin_amdgcn_s_barrier();

  for (int it = 0; it < K / 64; ++it) {
    const int buf = it & 1;
    if (it < K / 64 - 1) stage(buf ^ 1, (it + 1) * 64);
    const int rsel = ln & 15;
    #pragma unroll
    for (int kk = 0; kk < 2; ++kk) {
      const int ko = kk * 32 + (ln >> 4) * 8;
      bf16x8 af[4], bfr[4];
      #pragma unroll
      for (int m = 0; m < 4; ++m)
        af[m] = *(const bf16x8*)&As[buf][swz(wr * 64 + m * 16 + rsel, ko)];
      #pragma unroll
      for (int n = 0; n < 4; ++n)
        bfr[n] = *(const bf16x8*)&Bs[buf][swz(wc * 64 + n * 16 + rsel, ko)];
      #pragma unroll
      for (int m = 0; m < 4; ++m)
        #pragma unroll
        for (int n = 0; n < 4; ++n)
          acc[m][n] = __builtin_amdgcn_mfma_f32_16x16x32_bf16(af[m], bfr[n], acc[m][n], 0, 0, 0);
    }
    asm volatile("s_waitcnt vmcnt(0)" ::: "memory");
    __builtin_amdgcn_s_barrier();
  }

  const int cl = ln & 15, rg = (ln >> 4) * 4;
  const int which = cb >> 10;                 // 0=Q 1=K 2=V (block-uniform)
  const float sc = (which == 0) ? 0.125f : 1.0f;
  unsigned short* dst0 = qkv + (size_t)which * MR * DM;
  #pragma unroll
  for (int m = 0; m < 4; ++m) {
    #pragma unroll
    for (int i = 0; i < 4; ++i) {
      const int r = rb + wr * 64 + m * 16 + rg + i;
      const int b = r >> 11, s = r & 2047;
      #pragma unroll
      for (int n = 0; n < 4; ++n) {
        const int c = cb + wc * 64 + n * 16 + cl;
        const float v = (acc[m][n][i] + cbias[c]) * sc;
        const int cc = c & 1023, h = cc >> 6, d = c & 63;
        dst0[(((size_t)(b * NH + h)) * SQ + s) * DK + d] = f2bf(v);
      }
    }
  }
}

// -------- bf16 MFMA GEMM (final projection), 2-phase dbuf --------
__global__ __launch_bounds__(256)
void mfma_gemm_out(const unsigned short* __restrict__ A, const unsigned short* __restrict__ Bt,
                   const float* __restrict__ bias, float* __restrict__ outp)
{
  constexpr int K = DM, N = DM;
  __shared__ unsigned short As[2][128 * 64];
  __shared__ unsigned short Bs[2][128 * 64];
  const int t = threadIdx.x;
  const int w = t >> 6, ln = t & 63;
  const int wr = w >> 1, wc = w & 1;
  const int rb = blockIdx.y * 128, cb = blockIdx.x * 128;

  f32x4 acc[4][4] = {};

  auto stage = [&](int buf, int k0) {
    #pragma unroll
    for (int j = 0; j < 4; ++j) {
      const int rows8 = (w * 4 + j) * 8;
      const int r = rows8 + (ln >> 3);
      const int gc = (((ln & 7) ^ fswz(r)) & 7) * 8;
      __builtin_amdgcn_global_load_lds(
          (const __attribute__((address_space(1))) void*)&A[(size_t)(rb + r) * K + k0 + gc],
          (__attribute__((address_space(3))) void*)&As[buf][rows8 * 64], 16, 0, 0);
      __builtin_amdgcn_global_load_lds(
          (const __attribute__((address_space(1))) void*)&Bt[(size_t)(cb + r) * K + k0 + gc],
          (__attribute__((address_space(3))) void*)&Bs[buf][rows8 * 64], 16, 0, 0);
    }
  };

  stage(0, 0);
  asm volatile("s_waitcnt vmcnt(0)" ::: "memory");
  __builtin_amdgcn_s_barrier();

  for (int it = 0; it < K / 64; ++it) {
    const int buf = it & 1;
    if (it < K / 64 - 1) stage(buf ^ 1, (it + 1) * 64);
    const int rsel = ln & 15;
    #pragma unroll
    for (int kk = 0; kk < 2; ++kk) {
      const int ko = kk * 32 + (ln >> 4) * 8;
      bf16x8 af[4], bfr[4];
      #pragma unroll
      for (int m = 0; m < 4; ++m)
        af[m] = *(const bf16x8*)&As[buf][swz(wr * 64 + m * 16 + rsel, ko)];
      #pragma unroll
      for (int n = 0; n < 4; ++n)
        bfr[n] = *(const bf16x8*)&Bs[buf][swz(wc * 64 + n * 16 + rsel, ko)];
      #pragma unroll
      for (int m = 0; m < 4; ++m)
        #pragma unroll
        for (int n = 0; n < 4; ++n)
          acc[m][n] = __builtin_amdgcn_mfma_f32_16x16x32_bf16(af[m], bfr[n], acc[m][n], 0, 0, 0);
    }
    asm volatile("s_waitcnt vmcnt(0)" ::: "memory");
    __builtin_amdgcn_s_barrier();
  }

  const int cl = ln & 15, rg = (ln >> 4) * 4;
  #pragma unroll
  for (int m = 0; m < 4; ++m) {
    #pragma unroll
    for (int i = 0; i < 4; ++i) {
      const int r = rb + wr * 64 + m * 16 + rg + i;
      #pragma unroll
      for (int n = 0; n < 4; ++n) {
        const int c = cb + wc * 64 + n * 16 + cl;
        outp[(size_t)r * N + c] = acc[m][n][i] + bias[c];
      }
    }
  }
}

// -------- MFMA flash attention, 32x32, in-reg softmax, in-block KV-split --------
// 1024 threads = 16 waves: 8 q-waves x 2 KV partitions (each 1024 kv).
// Per wave: 32 q-rows. KV chunks of 128 (2 tiles), gll-staged, double-buffered.
// Part-1 dumps unnormalized O/m/l to LDS; part-0 combines exactly and stores.
__global__ __launch_bounds__(1024, 4)
void attn_split(const unsigned short* __restrict__ Qp, const unsigned short* __restrict__ Kp,
                const unsigned short* __restrict__ VTp, unsigned short* __restrict__ ctx)
{
  __shared__ unsigned short lds[65536];   // 128 KB
  const int t = threadIdx.x, w = t >> 6, ln = t & 63;
  const int lh = ln >> 5;
  const int part = w >> 3, qw = w & 7, tp = t & 511;
  const int bh = blockIdx.x, q0 = blockIdx.y * 256;
  const int b = bh >> 4, h = bh & 15;
  const unsigned short* Qb = Qp + (size_t)bh * SQ * DK;
  const unsigned short* Kb = Kp + (size_t)bh * SQ * DK;
  const unsigned short* Vb = VTp + (size_t)bh * DK * SQ;   // [DK][SQ]
  const int kvbase = part * (SQ / 2);

  // ---- stage Q [256][64] swizzled at lds[0..16384), hoist this wave's frags ----
  #pragma unroll
  for (int i = 0; i < 2; ++i) {
    int g = t + i * 1024, r = g >> 3, cg = g & 7;
    uint4 qv = *(const uint4*)&Qb[(size_t)(q0 + r) * DK + cg * 8];
    *(uint4*)&lds[r * 64 + (((cg ^ fswz(r)) & 7) << 3)] = qv;
  }
  __syncthreads();
  bf16x8 qf[4];
  #pragma unroll
  for (int s = 0; s < 4; ++s)
    qf[s] = *(const bf16x8*)&lds[swz(qw * 32 + (ln & 31), s * 16 + lh * 8)];
  __syncthreads();

  // per-partition LDS tiles: K [2buf][128][64] 16KB each, V^T [2buf][64][128]
  unsigned short* KsB[2] = { lds + (part * 2 + 0) * 8192, lds + (part * 2 + 1) * 8192 };
  unsigned short* VtB[2] = { lds + 32768 + (part * 2 + 0) * 8192,
                             lds + 32768 + (part * 2 + 1) * 8192 };

  f32x16 o0 = {}, o1 = {};     // O[q(reg)][d = (ln&31)] and [d = 32+(ln&31)]
  float m = -1e30f, l = 0.f;   // per-lane state for q = ln&31

  auto stage = [&](int buf, int ck) {
    #pragma unroll
    for (int j = 0; j < 2; ++j) {
      int g = tp + j * 512;
      int r = g >> 3, gc = ((g & 7) ^ fswz(r)) & 7;
      __builtin_amdgcn_global_load_lds(
          (const __attribute__((address_space(1))) void*)
              &Kb[(size_t)(kvbase + ck * 128 + r) * DK + gc * 8],
          (__attribute__((address_space(3))) void*)(KsB[buf] + (qw * 64 + j * 512) * 8),
          16, 0, 0);
      int d = g >> 4, c = g & 15;
      int cs = (c & 8) | ((c ^ fswz(d)) & 7);
      __builtin_amdgcn_global_load_lds(
          (const __attribute__((address_space(1))) void*)
              &Vb[(size_t)d * SQ + kvbase + ck * 128 + cs * 8],
          (__attribute__((address_space(3))) void*)(VtB[buf] + (qw * 64 + j * 512) * 8),
          16, 0, 0);
    }
  };

  stage(0, 0);
  asm volatile("s_waitcnt vmcnt(0)" ::: "memory");
  __builtin_amdgcn_s_barrier();

  int buf = 0;
  for (int ck = 0; ck < 8; ++ck) {
    if (ck < 7) stage(buf ^ 1, ck + 1);   // lands under compute
    #pragma unroll
    for (int it = 0; it < 2; ++it) {
      // ---- QK^T: S^T[kv 64][q 32] ----
      f32x16 s0 = {}, s1 = {};
      __builtin_amdgcn_s_setprio(1);
      #pragma unroll
      for (int s = 0; s < 4; ++s) {
        bf16x8 k0 = *(const bf16x8*)&KsB[buf][swz(it * 64 + (ln & 31), s * 16 + lh * 8)];
        bf16x8 k1 = *(const bf16x8*)&KsB[buf][swz(it * 64 + 32 + (ln & 31), s * 16 + lh * 8)];
        s0 = __builtin_amdgcn_mfma_f32_32x32x16_bf16(k0, qf[s], s0, 0, 0, 0);
        s1 = __builtin_amdgcn_mfma_f32_32x32x16_bf16(k1, qf[s], s1, 0, 0, 0);
      }
      __builtin_amdgcn_s_setprio(0);

      // ---- online softmax for q = ln&31 ----
      float mx0 = fmaxf(s0[0], s0[1]), mx1 = fmaxf(s0[2], s0[3]);
      #pragma unroll
      for (int j = 4; j < 16; j += 4) {
        mx0 = fmaxf(mx0, fmaxf(s0[j], s0[j + 1]));
        mx1 = fmaxf(mx1, fmaxf(s0[j + 2], s0[j + 3]));
      }
      #pragma unroll
      for (int j = 0; j < 16; j += 4) {
        mx0 = fmaxf(mx0, fmaxf(s1[j], s1[j + 1]));
        mx1 = fmaxf(mx1, fmaxf(s1[j + 2], s1[j + 3]));
      }
      float tm = fmaxf(mx0, mx1);
      tm = fmaxf(tm, __shfl_xor(tm, 32));

      if (__any((tm - m) > 8.f)) {  // defer-max (THR=8)
        const float mnew = fmaxf(m, tm);
        const float corr = __expf(m - mnew);
        float ci[16];
        #pragma unroll
        for (int j = 0; j < 16; ++j)
          ci[j] = __shfl(corr, (j & 3) + 8 * (j >> 2) + 4 * lh);
        #pragma unroll
        for (int j = 0; j < 16; ++j) { o0[j] *= ci[j]; o1[j] *= ci[j]; }
        l *= corr;
        m = mnew;
      }

      float p0[16], p1[16];
      #pragma unroll
      for (int j = 0; j < 16; ++j) {
        p0[j] = __expf(s0[j] - m);
        p1[j] = __expf(s1[j] - m);
      }
      float ps = 0.f;
      #pragma unroll
      for (int j = 0; j < 16; ++j) ps += p0[j] + p1[j];
      ps += __shfl_xor(ps, 32);
      l += ps;

      // ---- PV: A-frags from regs (cvt_pk + permlane32_swap), B from Vt ----
      __builtin_amdgcn_s_setprio(1);
      #pragma unroll
      for (int s = 0; s < 4; ++s) {
        unsigned w0, w1, w2, w3;
        if (s == 0) {
          asm("v_cvt_pk_bf16_f32 %0, %1, %2" : "=v"(w0) : "v"(p0[0]), "v"(p0[1]));
          asm("v_cvt_pk_bf16_f32 %0, %1, %2" : "=v"(w1) : "v"(p0[2]), "v"(p0[3]));
          asm("v_cvt_pk_bf16_f32 %0, %1, %2" : "=v"(w2) : "v"(p0[4]), "v"(p0[5]));
          asm("v_cvt_pk_bf16_f32 %0, %1, %2" : "=v"(w3) : "v"(p0[6]), "v"(p0[7]));
        } else if (s == 1) {
          asm("v_cvt_pk_bf16_f32 %0, %1, %2" : "=v"(w0) : "v"(p0[8]), "v"(p0[9]));
          asm("v_cvt_pk_bf16_f32 %0, %1, %2" : "=v"(w1) : "v"(p0[10]), "v"(p0[11]));
          asm("v_cvt_pk_bf16_f32 %0, %1, %2" : "=v"(w2) : "v"(p0[12]), "v"(p0[13]));
          asm("v_cvt_pk_bf16_f32 %0, %1, %2" : "=v"(w3) : "v"(p0[14]), "v"(p0[15]));
        } else if (s == 2) {
          asm("v_cvt_pk_bf16_f32 %0, %1, %2" : "=v"(w0) : "v"(p1[0]), "v"(p1[1]));
          asm("v_cvt_pk_bf16_f32 %0, %1, %2" : "=v"(w1) : "v"(p1[2]), "v"(p1[3]));
          asm("v_cvt_pk_bf16_f32 %0, %1, %2" : "=v"(w2) : "v"(p1[4]), "v"(p1[5]));
          asm("v_cvt_pk_bf16_f32 %0, %1, %2" : "=v"(w3) : "v"(p1[6]), "v"(p1[7]));
        } else {
          asm("v_cvt_pk_bf16_f32 %0, %1, %2" : "=v"(w0) : "v"(p1[8]), "v"(p1[9]));
          asm("v_cvt_pk_bf16_f32 %0, %1, %2" : "=v"(w1) : "v"(p1[10]), "v"(p1[11]));
          asm("v_cvt_pk_bf16_f32 %0, %1, %2" : "=v"(w2) : "v"(p1[12]), "v"(p1[13]));
          asm("v_cvt_pk_bf16_f32 %0, %1, %2" : "=v"(w3) : "v"(p1[14]), "v"(p1[15]));
        }
        asm("v_permlane32_swap_b32 %0, %1" : "+v"(w0), "+v"(w2));
        asm("v_permlane32_swap_b32 %0, %1" : "+v"(w1), "+v"(w3));
        union { unsigned u[4]; bf16x8 v; } pa;
        pa.u[0] = w0; pa.u[1] = w1; pa.u[2] = w2; pa.u[3] = w3;
        const int gx = it * 8 + s * 2 + lh;
        bf16x8 v0 = *(const bf16x8*)&VtB[buf][(ln & 31) * 128 + vslot(ln & 31, gx) * 8];
        bf16x8 v1 = *(const bf16x8*)&VtB[buf][(32 + (ln & 31)) * 128 + vslot(32 + (ln & 31), gx) * 8];
        o0 = __builtin_amdgcn_mfma_f32_32x32x16_bf16(pa.v, v0, o0, 0, 0, 0);
        o1 = __builtin_amdgcn_mfma_f32_32x32x16_bf16(pa.v, v1, o1, 0, 0, 0);
      }
      __builtin_amdgcn_s_setprio(0);
    }
    asm volatile("s_waitcnt vmcnt(0)" ::: "memory");  // prefetch landed
    __builtin_amdgcn_s_barrier();                     // all waves done with buf
    buf ^= 1;
  }

  // ---- in-LDS partition combine ----
  float* Obuf = (float*)lds;                 // 8 waves x 2048 f32 = 64 KB
  float* mlb  = (float*)&lds[32768];         // 8 waves x 128 f32 = 4 KB
  if (part == 1) {
    #pragma unroll
    for (int j = 0; j < 16; ++j) {
      Obuf[qw * 2048 + j * 64 + ln]        = o0[j];
      Obuf[qw * 2048 + (16 + j) * 64 + ln] = o1[j];
    }
    mlb[qw * 128 + ln * 2]     = m;
    mlb[qw * 128 + ln * 2 + 1] = l;
  }
  __syncthreads();
  if (part == 0) {
    const float m1 = mlb[qw * 128 + ln * 2];
    const float l1 = mlb[qw * 128 + ln * 2 + 1];
    const float M  = fmaxf(m, m1);
    const float e0 = __expf(m - M), e1 = __expf(m1 - M);
    const float rl = 1.0f / (l * e0 + l1 * e1);
    const float f0 = e0 * rl, f1 = e1 * rl;
    #pragma unroll
    for (int j = 0; j < 16; ++j) {
      const int crow = (j & 3) + 8 * (j >> 2) + 4 * lh;
      const float a0 = __shfl(f0, crow);
      const float a1 = __shfl(f1, crow);
      const float v0 = o0[j] * a0 + Obuf[qw * 2048 + j * 64 + ln] * a1;
      const float v1 = o1[j] * a0 + Obuf[qw * 2048 + (16 + j) * 64 + ln] * a1;
      const int srow = q0 + qw * 32 + crow;
      unsigned short* dst = ctx + ((size_t)(b * SQ + srow)) * DM + h * 64;
      dst[ln & 31]        = f2bf(v0);
      dst[32 + (ln & 31)] = f2bf(v1);
    }
  }
}

extern "C" void kernel_launch(void* const* d_in, const int* in_sizes, int n_in,
                              void* d_out, int out_size, void* d_ws, size_t ws_size,
                              hipStream_t stream) {
  const float* x  = (const float*)d_in[0];
  const float* Wq = (const float*)d_in[1];
  const float* bq = (const float*)d_in[2];
  const float* Wk = (const float*)d_in[3];
  const float* bk = (const float*)d_in[4];
  const float* Wv = (const float*)d_in[5];
  const float* bv = (const float*)d_in[6];
  const float* Wo = (const float*)d_in[7];
  const float* bo = (const float*)d_in[8];
  float* out = (float*)d_out;

  unsigned short* xb    = (unsigned short*)d_ws;             // [MR,DM] bf16, 8MB
  unsigned short* Wt3   = xb   + (size_t)MR * DM;            // [3072,1024] bf16, 6MB
  unsigned short* Wto   = Wt3  + (size_t)3 * DM * DM;        // [1024,1024] bf16, 2MB
  unsigned short* QKVb  = Wto  + (size_t)DM * DM;            // 3x [B,H,S,DK] bf16, 24MB
  unsigned short* Vtb   = QKVb + (size_t)3 * MR * DM;        // [B,H,DK,S] bf16, 8MB
  unsigned short* ctxb  = Vtb  + (size_t)MR * DM;            // [B,S,DM] bf16, 8MB
  float*          cbias = (float*)(ctxb + (size_t)MR * DM);  // [3072] f32
  // total ~56 MB

  cast_kernel<<<(MR * DM / 8 + 255) / 256, 256, 0, stream>>>(x, xb, MR * DM / 8);
  dim3 tg(DM / 32, DM / 32);
  transpose_cast_kernel<<<tg, 256, 0, stream>>>(Wq, Wt3);
  transpose_cast_kernel<<<tg, 256, 0, stream>>>(Wk, Wt3 + (size_t)DM * DM);
  transpose_cast_kernel<<<tg, 256, 0, stream>>>(Wv, Wt3 + (size_t)2 * DM * DM);
  transpose_cast_kernel<<<tg, 256, 0, stream>>>(Wo, Wto);
  concat_bias<<<12, 256, 0, stream>>>(bq, bk, bv, cbias);

  qkv_gemm<<<dim3(3 * DM / 128, MR / 128), 256, 0, stream>>>(xb, Wt3, cbias, QKVb);
  transpose_v<<<dim3(SQ / 64, BB * NH), 256, 0, stream>>>(
      QKVb + (size_t)2 * MR * DM, Vtb);

  attn_split<<<dim3(BB * NH, SQ / 256), 1024, 0, stream>>>(
      QKVb, QKVb + (size_t)MR * DM, Vtb, ctxb);

  mfma_gemm_out<<<dim3(DM / 128, MR / 128), 256, 0, stream>>>(ctxb, Wto, bo, out);
}

// Round 15
// 316.448 us; speedup vs baseline: 1.0043x; 1.0043x over previous
//
#include <hip/hip_runtime.h>
#include <hip/hip_bf16.h>
#include <math.h>

constexpr int DM = 1024;    // d_model
constexpr int NH = 16;      // heads
constexpr int DK = 64;      // head dim
constexpr int SQ = 2048;    // seq len
constexpr int BB = 2;       // batch
constexpr int MR = BB * SQ; // 4096 rows

typedef short bf16x8 __attribute__((ext_vector_type(8)));
typedef float f32x4 __attribute__((ext_vector_type(4)));
typedef float f32x16 __attribute__((ext_vector_type(16)));

__device__ inline unsigned short f2bf(float f) {
  unsigned u = __float_as_uint(f);
  unsigned r = (u + 0x7fffu + ((u >> 16) & 1u)) >> 16;  // RNE
  return (unsigned short)r;
}

// XOR swizzle for [R][64] bf16 LDS tiles. f(r) xors the 16B-granule index.
__device__ inline int fswz(int r) { return (r & 7) ^ ((r >> 3) & 7); }
__device__ inline int swz(int r, int c) {
  return r * 64 + ((((c >> 3) ^ fswz(r)) & 7) << 3) + (c & 7);
}
// [64][128] V^T tile: 16 granules/row, xor low 3 bits of granule index.
__device__ inline int vslot(int d, int g) { return (g & 8) | ((g ^ fswz(d)) & 7); }

// -------- cast f32 -> bf16, 8 elems/thread --------
__global__ __launch_bounds__(256)
void cast_kernel(const float* __restrict__ in, unsigned short* __restrict__ out, int n8) {
  int i = blockIdx.x * 256 + threadIdx.x;
  if (i >= n8) return;
  float4 a = *(const float4*)&in[(size_t)i * 8];
  float4 b = *(const float4*)&in[(size_t)i * 8 + 4];
  ushort4 lo = {f2bf(a.x), f2bf(a.y), f2bf(a.z), f2bf(a.w)};
  ushort4 hi = {f2bf(b.x), f2bf(b.y), f2bf(b.z), f2bf(b.w)};
  *(ushort4*)&out[(size_t)i * 8] = lo;
  *(ushort4*)&out[(size_t)i * 8 + 4] = hi;
}

// -------- cast+transpose: W[K][N] f32 -> Wt[N][K] bf16 (32x32 tiles) --------
__global__ __launch_bounds__(256)
void transpose_cast_kernel(const float* __restrict__ W, unsigned short* __restrict__ Wt) {
  __shared__ float tl[32][33];
  const int tx = threadIdx.x & 31, ty = threadIdx.x >> 5;  // 32 x 8
  const int x0 = blockIdx.x * 32, y0 = blockIdx.y * 32;    // x0: n, y0: k
  #pragma unroll
  for (int i = 0; i < 4; ++i)
    tl[ty + i * 8][tx] = W[(size_t)(y0 + ty + i * 8) * DM + x0 + tx];
  __syncthreads();
  #pragma unroll
  for (int i = 0; i < 4; ++i)
    Wt[(size_t)(x0 + ty + i * 8) * DM + y0 + tx] = f2bf(tl[tx][ty + i * 8]);
}

// -------- concat bias [bq|bk|bv] -> cb[3072] --------
__global__ __launch_bounds__(256)
void concat_bias(const float* __restrict__ bq, const float* __restrict__ bk,
                 const float* __restrict__ bv, float* __restrict__ cb) {
  int i = blockIdx.x * 256 + threadIdx.x;
  if (i < 1024) cb[i] = bq[i];
  else if (i < 2048) cb[i] = bk[i - 1024];
  else if (i < 3072) cb[i] = bv[i - 2048];
}

// -------- V transpose: [B,H,S,DK] -> [B,H,DK,S], 64x64 bf16 tiles --------
__global__ __launch_bounds__(256)
void transpose_v(const unsigned short* __restrict__ V, unsigned short* __restrict__ Vt) {
  __shared__ unsigned short tl[64 * 64];
  const int t = threadIdx.x;
  const int s0 = blockIdx.x * 64, bh = blockIdx.y;
  const unsigned short* src = V + (size_t)bh * SQ * DK;
  unsigned short* dst = Vt + (size_t)bh * DK * SQ;
  #pragma unroll
  for (int i = 0; i < 2; ++i) {
    int g = t + i * 256, r = g >> 3, cg = g & 7;
    uint4 v = *(const uint4*)&src[(size_t)(s0 + r) * DK + cg * 8];
    *(uint4*)&tl[r * 64 + (((cg ^ fswz(r)) & 7) << 3)] = v;
  }
  __syncthreads();
  #pragma unroll
  for (int i = 0; i < 2; ++i) {
    int g = t + i * 256, d = g >> 3, cs = g & 7;
    uint4 o;
    unsigned short* op = (unsigned short*)&o;
    #pragma unroll
    for (int e = 0; e < 8; ++e)
      op[e] = tl[swz(cs * 8 + e, d)];
    *(uint4*)&dst[(size_t)d * SQ + s0 + cs * 8] = o;
  }
}

// -------- fused QKV GEMM: [4096,1024] x Wt3[3072,1024]^T, 2-phase dbuf --------
__global__ __launch_bounds__(256)
void qkv_gemm(const unsigned short* __restrict__ A, const unsigned short* __restrict__ Wt3,
              const float* __restrict__ cbias, unsigned short* __restrict__ qkv)
{
  constexpr int K = DM;
  __shared__ unsigned short As[2][128 * 64];
  __shared__ unsigned short Bs[2][128 * 64];
  const int t = threadIdx.x;
  const int w = t >> 6, ln = t & 63;
  const int wr = w >> 1, wc = w & 1;
  const int rb = blockIdx.y * 128, cb = blockIdx.x * 128;

  f32x4 acc[4][4] = {};

  auto stage = [&](int buf, int k0) {
    #pragma unroll
    for (int j = 0; j < 4; ++j) {
      const int rows8 = (w * 4 + j) * 8;
      const int r = rows8 + (ln >> 3);
      const int gc = (((ln & 7) ^ fswz(r)) & 7) * 8;
      __builtin_amdgcn_global_load_lds(
          (const __attribute__((address_space(1))) void*)&A[(size_t)(rb + r) * K + k0 + gc],
          (__attribute__((address_space(3))) void*)&As[buf][rows8 * 64], 16, 0, 0);
      __builtin_amdgcn_global_load_lds(
          (const __attribute__((address_space(1))) void*)&Wt3[(size_t)(cb + r) * K + k0 + gc],
          (__attribute__((address_space(3))) void*)&Bs[buf][rows8 * 64], 16, 0, 0);
    }
  };

  stage(0, 0);
  asm volatile("s_waitcnt vmcnt(0)" ::: "memory");
  __builtin_amdgcn_s_barrier();

  for (int it = 0; it < K / 64; ++it) {
    const int buf = it & 1;
    if (it < K / 64 - 1) stage(buf ^ 1, (it + 1) * 64);
    const int rsel = ln & 15;
    #pragma unroll
    for (int kk = 0; kk < 2; ++kk) {
      const int ko = kk * 32 + (ln >> 4) * 8;
      bf16x8 af[4], bfr[4];
      #pragma unroll
      for (int m = 0; m < 4; ++m)
        af[m] = *(const bf16x8*)&As[buf][swz(wr * 64 + m * 16 + rsel, ko)];
      #pragma unroll
      for (int n = 0; n < 4; ++n)
        bfr[n] = *(const bf16x8*)&Bs[buf][swz(wc * 64 + n * 16 + rsel, ko)];
      #pragma unroll
      for (int m = 0; m < 4; ++m)
        #pragma unroll
        for (int n = 0; n < 4; ++n)
          acc[m][n] = __builtin_amdgcn_mfma_f32_16x16x32_bf16(af[m], bfr[n], acc[m][n], 0, 0, 0);
    }
    asm volatile("s_waitcnt vmcnt(0)" ::: "memory");
    __builtin_amdgcn_s_barrier();
  }

  const int cl = ln & 15, rg = (ln >> 4) * 4;
  const int which = cb >> 10;                 // 0=Q 1=K 2=V (block-uniform)
  const float sc = (which == 0) ? 0.125f : 1.0f;
  unsigned short* dst0 = qkv + (size_t)which * MR * DM;
  #pragma unroll
  for (int m = 0; m < 4; ++m) {
    #pragma unroll
    for (int i = 0; i < 4; ++i) {
      const int r = rb + wr * 64 + m * 16 + rg + i;
      const int b = r >> 11, s = r & 2047;
      #pragma unroll
      for (int n = 0; n < 4; ++n) {
        const int c = cb + wc * 64 + n * 16 + cl;
        const float v = (acc[m][n][i] + cbias[c]) * sc;
        const int cc = c & 1023, h = cc >> 6, d = c & 63;
        dst0[(((size_t)(b * NH + h)) * SQ + s) * DK + d] = f2bf(v);
      }
    }
  }
}

// -------- bf16 MFMA GEMM (final projection), 2-phase dbuf --------
__global__ __launch_bounds__(256)
void mfma_gemm_out(const unsigned short* __restrict__ A, const unsigned short* __restrict__ Bt,
                   const float* __restrict__ bias, float* __restrict__ outp)
{
  constexpr int K = DM, N = DM;
  __shared__ unsigned short As[2][128 * 64];
  __shared__ unsigned short Bs[2][128 * 64];
  const int t = threadIdx.x;
  const int w = t >> 6, ln = t & 63;
  const int wr = w >> 1, wc = w & 1;
  const int rb = blockIdx.y * 128, cb = blockIdx.x * 128;

  f32x4 acc[4][4] = {};

  auto stage = [&](int buf, int k0) {
    #pragma unroll
    for (int j = 0; j < 4; ++j) {
      const int rows8 = (w * 4 + j) * 8;
      const int r = rows8 + (ln >> 3);
      const int gc = (((ln & 7) ^ fswz(r)) & 7) * 8;
      __builtin_amdgcn_global_load_lds(
          (const __attribute__((address_space(1))) void*)&A[(size_t)(rb + r) * K + k0 + gc],
          (__attribute__((address_space(3))) void*)&As[buf][rows8 * 64], 16, 0, 0);
      __builtin_amdgcn_global_load_lds(
          (const __attribute__((address_space(1))) void*)&Bt[(size_t)(cb + r) * K + k0 + gc],
          (__attribute__((address_space(3))) void*)&Bs[buf][rows8 * 64], 16, 0, 0);
    }
  };

  stage(0, 0);
  asm volatile("s_waitcnt vmcnt(0)" ::: "memory");
  __builtin_amdgcn_s_barrier();

  for (int it = 0; it < K / 64; ++it) {
    const int buf = it & 1;
    if (it < K / 64 - 1) stage(buf ^ 1, (it + 1) * 64);
    const int rsel = ln & 15;
    #pragma unroll
    for (int kk = 0; kk < 2; ++kk) {
      const int ko = kk * 32 + (ln >> 4) * 8;
      bf16x8 af[4], bfr[4];
      #pragma unroll
      for (int m = 0; m < 4; ++m)
        af[m] = *(const bf16x8*)&As[buf][swz(wr * 64 + m * 16 + rsel, ko)];
      #pragma unroll
      for (int n = 0; n < 4; ++n)
        bfr[n] = *(const bf16x8*)&Bs[buf][swz(wc * 64 + n * 16 + rsel, ko)];
      #pragma unroll
      for (int m = 0; m < 4; ++m)
        #pragma unroll
        for (int n = 0; n < 4; ++n)
          acc[m][n] = __builtin_amdgcn_mfma_f32_16x16x32_bf16(af[m], bfr[n], acc[m][n], 0, 0, 0);
    }
    asm volatile("s_waitcnt vmcnt(0)" ::: "memory");
    __builtin_amdgcn_s_barrier();
  }

  const int cl = ln & 15, rg = (ln >> 4) * 4;
  #pragma unroll
  for (int m = 0; m < 4; ++m) {
    #pragma unroll
    for (int i = 0; i < 4; ++i) {
      const int r = rb + wr * 64 + m * 16 + rg + i;
      #pragma unroll
      for (int n = 0; n < 4; ++n) {
        const int c = cb + wc * 64 + n * 16 + cl;
        outp[(size_t)r * N + c] = acc[m][n][i] + bias[c];
      }
    }
  }
}

// -------- MFMA flash attention, 32x32, in-reg softmax, in-block KV-split --------
// 1024 threads = 16 waves: 8 q-waves x 2 KV partitions (each 1024 kv).
// Per wave: 32 q-rows. KV chunks of 128 (2 tiles), gll-staged, double-buffered.
// Part-1 dumps unnormalized O/m/l to LDS; part-0 combines exactly and stores.
// launch_bounds WITHOUT a min-waves arg: 1-block residency implies a 128-VGPR
// cap (round 14's ",4" drove the allocator to 64 VGPRs -> catastrophic spills).
__global__ __launch_bounds__(1024)
void attn_split(const unsigned short* __restrict__ Qp, const unsigned short* __restrict__ Kp,
                const unsigned short* __restrict__ VTp, unsigned short* __restrict__ ctx)
{
  __shared__ unsigned short lds[65536];   // 128 KB
  const int t = threadIdx.x, w = t >> 6, ln = t & 63;
  const int lh = ln >> 5;
  const int part = w >> 3, qw = w & 7, tp = t & 511;
  const int bh = blockIdx.x, q0 = blockIdx.y * 256;
  const int b = bh >> 4, h = bh & 15;
  const unsigned short* Qb = Qp + (size_t)bh * SQ * DK;
  const unsigned short* Kb = Kp + (size_t)bh * SQ * DK;
  const unsigned short* Vb = VTp + (size_t)bh * DK * SQ;   // [DK][SQ]
  const int kvbase = part * (SQ / 2);

  // ---- stage Q [256][64] swizzled at lds[0..16384), hoist this wave's frags ----
  #pragma unroll
  for (int i = 0; i < 2; ++i) {
    int g = t + i * 1024, r = g >> 3, cg = g & 7;
    uint4 qv = *(const uint4*)&Qb[(size_t)(q0 + r) * DK + cg * 8];
    *(uint4*)&lds[r * 64 + (((cg ^ fswz(r)) & 7) << 3)] = qv;
  }
  __syncthreads();
  bf16x8 qf[4];
  #pragma unroll
  for (int s = 0; s < 4; ++s)
    qf[s] = *(const bf16x8*)&lds[swz(qw * 32 + (ln & 31), s * 16 + lh * 8)];
  __syncthreads();

  // per-partition LDS tiles: K [2buf][128][64] 16KB each, V^T [2buf][64][128]
  unsigned short* KsB[2] = { lds + (part * 2 + 0) * 8192, lds + (part * 2 + 1) * 8192 };
  unsigned short* VtB[2] = { lds + 32768 + (part * 2 + 0) * 8192,
                             lds + 32768 + (part * 2 + 1) * 8192 };

  f32x16 o0 = {}, o1 = {};     // O[q(reg)][d = (ln&31)] and [d = 32+(ln&31)]
  float m = -1e30f, l = 0.f;   // per-lane state for q = ln&31

  auto stage = [&](int buf, int ck) {
    #pragma unroll
    for (int j = 0; j < 2; ++j) {
      int g = tp + j * 512;
      int r = g >> 3, gc = ((g & 7) ^ fswz(r)) & 7;
      __builtin_amdgcn_global_load_lds(
          (const __attribute__((address_space(1))) void*)
              &Kb[(size_t)(kvbase + ck * 128 + r) * DK + gc * 8],
          (__attribute__((address_space(3))) void*)(KsB[buf] + (qw * 64 + j * 512) * 8),
          16, 0, 0);
      int d = g >> 4, c = g & 15;
      int cs = (c & 8) | ((c ^ fswz(d)) & 7);
      __builtin_amdgcn_global_load_lds(
          (const __attribute__((address_space(1))) void*)
              &Vb[(size_t)d * SQ + kvbase + ck * 128 + cs * 8],
          (__attribute__((address_space(3))) void*)(VtB[buf] + (qw * 64 + j * 512) * 8),
          16, 0, 0);
    }
  };

  stage(0, 0);
  asm volatile("s_waitcnt vmcnt(0)" ::: "memory");
  __builtin_amdgcn_s_barrier();

  int buf = 0;
  for (int ck = 0; ck < 8; ++ck) {
    if (ck < 7) stage(buf ^ 1, ck + 1);   // lands under compute
    #pragma unroll
    for (int it = 0; it < 2; ++it) {
      // ---- QK^T: S^T[kv 64][q 32] ----
      f32x16 s0 = {}, s1 = {};
      __builtin_amdgcn_s_setprio(1);
      #pragma unroll
      for (int s = 0; s < 4; ++s) {
        bf16x8 k0 = *(const bf16x8*)&KsB[buf][swz(it * 64 + (ln & 31), s * 16 + lh * 8)];
        bf16x8 k1 = *(const bf16x8*)&KsB[buf][swz(it * 64 + 32 + (ln & 31), s * 16 + lh * 8)];
        s0 = __builtin_amdgcn_mfma_f32_32x32x16_bf16(k0, qf[s], s0, 0, 0, 0);
        s1 = __builtin_amdgcn_mfma_f32_32x32x16_bf16(k1, qf[s], s1, 0, 0, 0);
      }
      __builtin_amdgcn_s_setprio(0);

      // ---- online softmax for q = ln&31 ----
      float mx0 = fmaxf(s0[0], s0[1]), mx1 = fmaxf(s0[2], s0[3]);
      #pragma unroll
      for (int j = 4; j < 16; j += 4) {
        mx0 = fmaxf(mx0, fmaxf(s0[j], s0[j + 1]));
        mx1 = fmaxf(mx1, fmaxf(s0[j + 2], s0[j + 3]));
      }
      #pragma unroll
      for (int j = 0; j < 16; j += 4) {
        mx0 = fmaxf(mx0, fmaxf(s1[j], s1[j + 1]));
        mx1 = fmaxf(mx1, fmaxf(s1[j + 2], s1[j + 3]));
      }
      float tm = fmaxf(mx0, mx1);
      tm = fmaxf(tm, __shfl_xor(tm, 32));

      if (__any((tm - m) > 8.f)) {  // defer-max (THR=8)
        const float mnew = fmaxf(m, tm);
        const float corr = __expf(m - mnew);
        float ci[16];
        #pragma unroll
        for (int j = 0; j < 16; ++j)
          ci[j] = __shfl(corr, (j & 3) + 8 * (j >> 2) + 4 * lh);
        #pragma unroll
        for (int j = 0; j < 16; ++j) { o0[j] *= ci[j]; o1[j] *= ci[j]; }
        l *= corr;
        m = mnew;
      }

      // exp in place (s0/s1 become P) — halves transient register pressure
      #pragma unroll
      for (int j = 0; j < 16; ++j) {
        s0[j] = __expf(s0[j] - m);
        s1[j] = __expf(s1[j] - m);
      }
      float ps = 0.f;
      #pragma unroll
      for (int j = 0; j < 16; ++j) ps += s0[j] + s1[j];
      ps += __shfl_xor(ps, 32);
      l += ps;

      // ---- PV: A-frags from regs (cvt_pk + permlane32_swap), B from Vt ----
      __builtin_amdgcn_s_setprio(1);
      #pragma unroll
      for (int s = 0; s < 4; ++s) {
        unsigned w0, w1, w2, w3;
        if (s == 0) {
          asm("v_cvt_pk_bf16_f32 %0, %1, %2" : "=v"(w0) : "v"(s0[0]), "v"(s0[1]));
          asm("v_cvt_pk_bf16_f32 %0, %1, %2" : "=v"(w1) : "v"(s0[2]), "v"(s0[3]));
          asm("v_cvt_pk_bf16_f32 %0, %1, %2" : "=v"(w2) : "v"(s0[4]), "v"(s0[5]));
          asm("v_cvt_pk_bf16_f32 %0, %1, %2" : "=v"(w3) : "v"(s0[6]), "v"(s0[7]));
        } else if (s == 1) {
          asm("v_cvt_pk_bf16_f32 %0, %1, %2" : "=v"(w0) : "v"(s0[8]), "v"(s0[9]));
          asm("v_cvt_pk_bf16_f32 %0, %1, %2" : "=v"(w1) : "v"(s0[10]), "v"(s0[11]));
          asm("v_cvt_pk_bf16_f32 %0, %1, %2" : "=v"(w2) : "v"(s0[12]), "v"(s0[13]));
          asm("v_cvt_pk_bf16_f32 %0, %1, %2" : "=v"(w3) : "v"(s0[14]), "v"(s0[15]));
        } else if (s == 2) {
          asm("v_cvt_pk_bf16_f32 %0, %1, %2" : "=v"(w0) : "v"(s1[0]), "v"(s1[1]));
          asm("v_cvt_pk_bf16_f32 %0, %1, %2" : "=v"(w1) : "v"(s1[2]), "v"(s1[3]));
          asm("v_cvt_pk_bf16_f32 %0, %1, %2" : "=v"(w2) : "v"(s1[4]), "v"(s1[5]));
          asm("v_cvt_pk_bf16_f32 %0, %1, %2" : "=v"(w3) : "v"(s1[6]), "v"(s1[7]));
        } else {
          asm("v_cvt_pk_bf16_f32 %0, %1, %2" : "=v"(w0) : "v"(s1[8]), "v"(s1[9]));
          asm("v_cvt_pk_bf16_f32 %0, %1, %2" : "=v"(w1) : "v"(s1[10]), "v"(s1[11]));
          asm("v_cvt_pk_bf16_f32 %0, %1, %2" : "=v"(w2) : "v"(s1[12]), "v"(s1[13]));
          asm("v_cvt_pk_bf16_f32 %0, %1, %2" : "=v"(w3) : "v"(s1[14]), "v"(s1[15]));
        }
        asm("v_permlane32_swap_b32 %0, %1" : "+v"(w0), "+v"(w2));
        asm("v_permlane32_swap_b32 %0, %1" : "+v"(w1), "+v"(w3));
        union { unsigned u[4]; bf16x8 v; } pa;
        pa.u[0] = w0; pa.u[1] = w1; pa.u[2] = w2; pa.u[3] = w3;
        const int gx = it * 8 + s * 2 + lh;
        bf16x8 v0 = *(const bf16x8*)&VtB[buf][(ln & 31) * 128 + vslot(ln & 31, gx) * 8];
        bf16x8 v1 = *(const bf16x8*)&VtB[buf][(32 + (ln & 31)) * 128 + vslot(32 + (ln & 31), gx) * 8];
        o0 = __builtin_amdgcn_mfma_f32_32x32x16_bf16(pa.v, v0, o0, 0, 0, 0);
        o1 = __builtin_amdgcn_mfma_f32_32x32x16_bf16(pa.v, v1, o1, 0, 0, 0);
      }
      __builtin_amdgcn_s_setprio(0);
    }
    asm volatile("s_waitcnt vmcnt(0)" ::: "memory");  // prefetch landed
    __builtin_amdgcn_s_barrier();                     // all waves done with buf
    buf ^= 1;
  }

  // ---- in-LDS partition combine ----
  float* Obuf = (float*)lds;                 // 8 waves x 2048 f32 = 64 KB
  float* mlb  = (float*)&lds[32768];         // 8 waves x 128 f32 = 4 KB
  if (part == 1) {
    #pragma unroll
    for (int j = 0; j < 16; ++j) {
      Obuf[qw * 2048 + j * 64 + ln]        = o0[j];
      Obuf[qw * 2048 + (16 + j) * 64 + ln] = o1[j];
    }
    mlb[qw * 128 + ln * 2]     = m;
    mlb[qw * 128 + ln * 2 + 1] = l;
  }
  __syncthreads();
  if (part == 0) {
    const float m1 = mlb[qw * 128 + ln * 2];
    const float l1 = mlb[qw * 128 + ln * 2 + 1];
    const float M  = fmaxf(m, m1);
    const float e0 = __expf(m - M), e1 = __expf(m1 - M);
    const float rl = 1.0f / (l * e0 + l1 * e1);
    const float f0 = e0 * rl, f1 = e1 * rl;
    #pragma unroll
    for (int j = 0; j < 16; ++j) {
      const int crow = (j & 3) + 8 * (j >> 2) + 4 * lh;
      const float a0 = __shfl(f0, crow);
      const float a1 = __shfl(f1, crow);
      const float v0 = o0[j] * a0 + Obuf[qw * 2048 + j * 64 + ln] * a1;
      const float v1 = o1[j] * a0 + Obuf[qw * 2048 + (16 + j) * 64 + ln] * a1;
      const int srow = q0 + qw * 32 + crow;
      unsigned short* dst = ctx + ((size_t)(b * SQ + srow)) * DM + h * 64;
      dst[ln & 31]        = f2bf(v0);
      dst[32 + (ln & 31)] = f2bf(v1);
    }
  }
}

extern "C" void kernel_launch(void* const* d_in, const int* in_sizes, int n_in,
                              void* d_out, int out_size, void* d_ws, size_t ws_size,
                              hipStream_t stream) {
  const float* x  = (const float*)d_in[0];
  const float* Wq = (const float*)d_in[1];
  const float* bq = (const float*)d_in[2];
  const float* Wk = (const float*)d_in[3];
  const float* bk = (const float*)d_in[4];
  const float* Wv = (const float*)d_in[5];
  const float* bv = (const float*)d_in[6];
  const float* Wo = (const float*)d_in[7];
  const float* bo = (const float*)d_in[8];
  float* out = (float*)d_out;

  unsigned short* xb    = (unsigned short*)d_ws;             // [MR,DM] bf16, 8MB
  unsigned short* Wt3   = xb   + (size_t)MR * DM;            // [3072,1024] bf16, 6MB
  unsigned short* Wto   = Wt3  + (size_t)3 * DM * DM;        // [1024,1024] bf16, 2MB
  unsigned short* QKVb  = Wto  + (size_t)DM * DM;            // 3x [B,H,S,DK] bf16, 24MB
  unsigned short* Vtb   = QKVb + (size_t)3 * MR * DM;        // [B,H,DK,S] bf16, 8MB
  unsigned short* ctxb  = Vtb  + (size_t)MR * DM;            // [B,S,DM] bf16, 8MB
  float*          cbias = (float*)(ctxb + (size_t)MR * DM);  // [3072] f32
  // total ~56 MB

  cast_kernel<<<(MR * DM / 8 + 255) / 256, 256, 0, stream>>>(x, xb, MR * DM / 8);
  dim3 tg(DM / 32, DM / 32);
  transpose_cast_kernel<<<tg, 256, 0, stream>>>(Wq, Wt3);
  transpose_cast_kernel<<<tg, 256, 0, stream>>>(Wk, Wt3 + (size_t)DM * DM);
  transpose_cast_kernel<<<tg, 256, 0, stream>>>(Wv, Wt3 + (size_t)2 * DM * DM);
  transpose_cast_kernel<<<tg, 256, 0, stream>>>(Wo, Wto);
  concat_bias<<<12, 256, 0, stream>>>(bq, bk, bv, cbias);

  qkv_gemm<<<dim3(3 * DM / 128, MR / 128), 256, 0, stream>>>(xb, Wt3, cbias, QKVb);
  transpose_v<<<dim3(SQ / 64, BB * NH), 256, 0, stream>>>(
      QKVb + (size_t)2 * MR * DM, Vtb);

  attn_split<<<dim3(BB * NH, SQ / 256), 1024, 0, stream>>>(
      QKVb, QKVb + (size_t)MR * DM, Vtb, ctxb);

  mfma_gemm_out<<<dim3(DM / 128, MR / 128), 256, 0, stream>>>(ctxb, Wto, bo, out);
}

// Round 16
// 168.114 us; speedup vs baseline: 1.8904x; 1.8823x over previous
//
#include <hip/hip_runtime.h>
#include <hip/hip_bf16.h>
#include <math.h>

constexpr int DM = 1024;    // d_model
constexpr int NH = 16;      // heads
constexpr int DK = 64;      // head dim
constexpr int SQ = 2048;    // seq len
constexpr int BB = 2;       // batch
constexpr int MR = BB * SQ; // 4096 rows

typedef short bf16x8 __attribute__((ext_vector_type(8)));
typedef float f32x4 __attribute__((ext_vector_type(4)));

__device__ inline unsigned short f2bf(float f) {
  unsigned u = __float_as_uint(f);
  unsigned r = (u + 0x7fffu + ((u >> 16) & 1u)) >> 16;  // RNE
  return (unsigned short)r;
}

// XOR swizzle for [R][64] bf16 LDS tiles. f(r) xors the 16B-granule index.
__device__ inline int fswz(int r) { return (r & 7) ^ ((r >> 3) & 7); }
__device__ inline int swz(int r, int c) {
  return r * 64 + ((((c >> 3) ^ fswz(r)) & 7) << 3) + (c & 7);
}
// [64][128] V^T tile: 16 granules/row; bijective slot map per row.
__device__ inline int vslot(int d, int g) { return (g & 8) | ((g ^ fswz(d)) & 7); }

// -------- cast f32 -> bf16, 8 elems/thread --------
__global__ __launch_bounds__(256)
void cast_kernel(const float* __restrict__ in, unsigned short* __restrict__ out, int n8) {
  int i = blockIdx.x * 256 + threadIdx.x;
  if (i >= n8) return;
  float4 a = *(const float4*)&in[(size_t)i * 8];
  float4 b = *(const float4*)&in[(size_t)i * 8 + 4];
  ushort4 lo = {f2bf(a.x), f2bf(a.y), f2bf(a.z), f2bf(a.w)};
  ushort4 hi = {f2bf(b.x), f2bf(b.y), f2bf(b.z), f2bf(b.w)};
  *(ushort4*)&out[(size_t)i * 8] = lo;
  *(ushort4*)&out[(size_t)i * 8 + 4] = hi;
}

// -------- cast+transpose all 4 weights: z picks {Wq,Wk,Wv,Wo} --------
__global__ __launch_bounds__(256)
void transpose_cast_all(const float* __restrict__ Wq, const float* __restrict__ Wk,
                        const float* __restrict__ Wv, const float* __restrict__ Wo,
                        unsigned short* __restrict__ Wt3, unsigned short* __restrict__ Wto) {
  __shared__ float tl[32][33];
  const int z = blockIdx.z;
  const float* W = (z == 0) ? Wq : (z == 1) ? Wk : (z == 2) ? Wv : Wo;
  unsigned short* Wt = (z < 3) ? (Wt3 + (size_t)z * DM * DM) : Wto;
  const int tx = threadIdx.x & 31, ty = threadIdx.x >> 5;  // 32 x 8
  const int x0 = blockIdx.x * 32, y0 = blockIdx.y * 32;    // x0: n, y0: k
  #pragma unroll
  for (int i = 0; i < 4; ++i)
    tl[ty + i * 8][tx] = W[(size_t)(y0 + ty + i * 8) * DM + x0 + tx];
  __syncthreads();
  #pragma unroll
  for (int i = 0; i < 4; ++i)
    Wt[(size_t)(x0 + ty + i * 8) * DM + y0 + tx] = f2bf(tl[tx][ty + i * 8]);
}

// -------- V transpose: [B,H,S,DK] -> [B,H,DK,S], 64x64 bf16 tiles --------
__global__ __launch_bounds__(256)
void transpose_v(const unsigned short* __restrict__ V, unsigned short* __restrict__ Vt) {
  __shared__ unsigned short tl[64 * 64];
  const int t = threadIdx.x;
  const int s0 = blockIdx.x * 64, bh = blockIdx.y;
  const unsigned short* src = V + (size_t)bh * SQ * DK;
  unsigned short* dst = Vt + (size_t)bh * DK * SQ;
  #pragma unroll
  for (int i = 0; i < 2; ++i) {
    int g = t + i * 256, r = g >> 3, cg = g & 7;
    uint4 v = *(const uint4*)&src[(size_t)(s0 + r) * DK + cg * 8];
    *(uint4*)&tl[r * 64 + (((cg ^ fswz(r)) & 7) << 3)] = v;
  }
  __syncthreads();
  #pragma unroll
  for (int i = 0; i < 2; ++i) {
    int g = t + i * 256, d = g >> 3, cs = g & 7;
    uint4 o;
    unsigned short* op = (unsigned short*)&o;
    #pragma unroll
    for (int e = 0; e < 8; ++e)
      op[e] = tl[swz(cs * 8 + e, d)];
    *(uint4*)&dst[(size_t)d * SQ + s0 + cs * 8] = o;
  }
}

// -------- fused QKV GEMM: [4096,1024] x Wt3[3072,1024]^T, 2-phase dbuf --------
// Q output scaled 1/8 (softmax scale folded). Bias selected by block column.
__global__ __launch_bounds__(256)
void qkv_gemm(const unsigned short* __restrict__ A, const unsigned short* __restrict__ Wt3,
              const float* __restrict__ bq, const float* __restrict__ bk,
              const float* __restrict__ bv, unsigned short* __restrict__ qkv)
{
  constexpr int K = DM;
  __shared__ unsigned short As[2][128 * 64];
  __shared__ unsigned short Bs[2][128 * 64];
  const int t = threadIdx.x;
  const int w = t >> 6, ln = t & 63;
  const int wr = w >> 1, wc = w & 1;
  const int rb = blockIdx.y * 128, cb = blockIdx.x * 128;

  f32x4 acc[4][4] = {};

  auto stage = [&](int buf, int k0) {
    #pragma unroll
    for (int j = 0; j < 4; ++j) {
      const int rows8 = (w * 4 + j) * 8;
      const int r = rows8 + (ln >> 3);
      const int gc = (((ln & 7) ^ fswz(r)) & 7) * 8;
      __builtin_amdgcn_global_load_lds(
          (const __attribute__((address_space(1))) void*)&A[(size_t)(rb + r) * K + k0 + gc],
          (__attribute__((address_space(3))) void*)&As[buf][rows8 * 64], 16, 0, 0);
      __builtin_amdgcn_global_load_lds(
          (const __attribute__((address_space(1))) void*)&Wt3[(size_t)(cb + r) * K + k0 + gc],
          (__attribute__((address_space(3))) void*)&Bs[buf][rows8 * 64], 16, 0, 0);
    }
  };

  stage(0, 0);
  asm volatile("s_waitcnt vmcnt(0)" ::: "memory");
  __builtin_amdgcn_s_barrier();

  for (int it = 0; it < K / 64; ++it) {
    const int buf = it & 1;
    if (it < K / 64 - 1) stage(buf ^ 1, (it + 1) * 64);
    const int rsel = ln & 15;
    #pragma unroll
    for (int kk = 0; kk < 2; ++kk) {
      const int ko = kk * 32 + (ln >> 4) * 8;
      bf16x8 af[4], bfr[4];
      #pragma unroll
      for (int m = 0; m < 4; ++m)
        af[m] = *(const bf16x8*)&As[buf][swz(wr * 64 + m * 16 + rsel, ko)];
      #pragma unroll
      for (int n = 0; n < 4; ++n)
        bfr[n] = *(const bf16x8*)&Bs[buf][swz(wc * 64 + n * 16 + rsel, ko)];
      #pragma unroll
      for (int m = 0; m < 4; ++m)
        #pragma unroll
        for (int n = 0; n < 4; ++n)
          acc[m][n] = __builtin_amdgcn_mfma_f32_16x16x32_bf16(af[m], bfr[n], acc[m][n], 0, 0, 0);
    }
    asm volatile("s_waitcnt vmcnt(0)" ::: "memory");
    __builtin_amdgcn_s_barrier();
  }

  const int cl = ln & 15, rg = (ln >> 4) * 4;
  const int which = cb >> 10;                 // 0=Q 1=K 2=V (block-uniform)
  const float sc = (which == 0) ? 0.125f : 1.0f;
  const float* bp = (which == 0) ? bq : (which == 1) ? bk : bv;
  unsigned short* dst0 = qkv + (size_t)which * MR * DM;
  #pragma unroll
  for (int m = 0; m < 4; ++m) {
    #pragma unroll
    for (int i = 0; i < 4; ++i) {
      const int r = rb + wr * 64 + m * 16 + rg + i;
      const int b = r >> 11, s = r & 2047;
      #pragma unroll
      for (int n = 0; n < 4; ++n) {
        const int c = cb + wc * 64 + n * 16 + cl;
        const int cc = c & 1023, h = cc >> 6, d = c & 63;
        const float v = (acc[m][n][i] + bp[cc]) * sc;
        dst0[(((size_t)(b * NH + h)) * SQ + s) * DK + d] = f2bf(v);
      }
    }
  }
}

// -------- bf16 MFMA GEMM (final projection), 2-phase dbuf --------
__global__ __launch_bounds__(256)
void mfma_gemm_out(const unsigned short* __restrict__ A, const unsigned short* __restrict__ Bt,
                   const float* __restrict__ bias, float* __restrict__ outp)
{
  constexpr int K = DM, N = DM;
  __shared__ unsigned short As[2][128 * 64];
  __shared__ unsigned short Bs[2][128 * 64];
  const int t = threadIdx.x;
  const int w = t >> 6, ln = t & 63;
  const int wr = w >> 1, wc = w & 1;
  const int rb = blockIdx.y * 128, cb = blockIdx.x * 128;

  f32x4 acc[4][4] = {};

  auto stage = [&](int buf, int k0) {
    #pragma unroll
    for (int j = 0; j < 4; ++j) {
      const int rows8 = (w * 4 + j) * 8;
      const int r = rows8 + (ln >> 3);
      const int gc = (((ln & 7) ^ fswz(r)) & 7) * 8;
      __builtin_amdgcn_global_load_lds(
          (const __attribute__((address_space(1))) void*)&A[(size_t)(rb + r) * K + k0 + gc],
          (__attribute__((address_space(3))) void*)&As[buf][rows8 * 64], 16, 0, 0);
      __builtin_amdgcn_global_load_lds(
          (const __attribute__((address_space(1))) void*)&Bt[(size_t)(cb + r) * K + k0 + gc],
          (__attribute__((address_space(3))) void*)&Bs[buf][rows8 * 64], 16, 0, 0);
    }
  };

  stage(0, 0);
  asm volatile("s_waitcnt vmcnt(0)" ::: "memory");
  __builtin_amdgcn_s_barrier();

  for (int it = 0; it < K / 64; ++it) {
    const int buf = it & 1;
    if (it < K / 64 - 1) stage(buf ^ 1, (it + 1) * 64);
    const int rsel = ln & 15;
    #pragma unroll
    for (int kk = 0; kk < 2; ++kk) {
      const int ko = kk * 32 + (ln >> 4) * 8;
      bf16x8 af[4], bfr[4];
      #pragma unroll
      for (int m = 0; m < 4; ++m)
        af[m] = *(const bf16x8*)&As[buf][swz(wr * 64 + m * 16 + rsel, ko)];
      #pragma unroll
      for (int n = 0; n < 4; ++n)
        bfr[n] = *(const bf16x8*)&Bs[buf][swz(wc * 64 + n * 16 + rsel, ko)];
      #pragma unroll
      for (int m = 0; m < 4; ++m)
        #pragma unroll
        for (int n = 0; n < 4; ++n)
          acc[m][n] = __builtin_amdgcn_mfma_f32_16x16x32_bf16(af[m], bfr[n], acc[m][n], 0, 0, 0);
    }
    asm volatile("s_waitcnt vmcnt(0)" ::: "memory");
    __builtin_amdgcn_s_barrier();
  }

  const int cl = ln & 15, rg = (ln >> 4) * 4;
  #pragma unroll
  for (int m = 0; m < 4; ++m) {
    #pragma unroll
    for (int i = 0; i < 4; ++i) {
      const int r = rb + wr * 64 + m * 16 + rg + i;
      #pragma unroll
      for (int n = 0; n < 4; ++n) {
        const int c = cb + wc * 64 + n * 16 + cl;
        outp[(size_t)r * N + c] = acc[m][n][i] + bias[c];
      }
    }
  }
}

// -------- MFMA flash attention: 8 waves, QBLK=128, KV-tile 128, V^T input --------
// Round-10 dataflow (16x16 MFMA, q=16/wave, swapped QK^T, Pl round-trip) with:
// KV tile doubled to 128 (half the barriers), V consumed from pre-transposed
// V^T (vectorized b128 staging, no scalar transpose), exp computed in place.
__global__ __launch_bounds__(512)
void attn_mfma(const unsigned short* __restrict__ Qp, const unsigned short* __restrict__ Kp,
               const unsigned short* __restrict__ VTp, unsigned short* __restrict__ ctx)
{
  __shared__ unsigned short Qs[128 * 64];     // 16KB
  __shared__ unsigned short Ks[128 * 64];     // 16KB (128 kv rows)
  __shared__ unsigned short Vt[64 * 128];     // 16KB ([d][kv 128])
  __shared__ unsigned short Pl[8 * 16 * 64];  // 16KB per-wave P: [q][kk]
  const int t = threadIdx.x, w = t >> 6, ln = t & 63;
  const int bh = blockIdx.y, q0 = blockIdx.x * 128;
  const unsigned short* Qb = Qp + (size_t)bh * SQ * DK;
  const unsigned short* Kb = Kp + (size_t)bh * SQ * DK;
  const unsigned short* Vb = VTp + (size_t)bh * DK * SQ;   // [DK][SQ]

  // stage Q tile: 128 rows x 64 = 1024 granules, 2/thread
  #pragma unroll
  for (int i = 0; i < 2; ++i) {
    int g = t + i * 512, r = g >> 3, cg = g & 7;
    uint4 qv = *(const uint4*)&Qb[(size_t)(q0 + r) * DK + cg * 8];
    *(uint4*)&Qs[r * 64 + (((cg ^ fswz(r)) & 7) << 3)] = qv;
  }
  __syncthreads();
  const int rsel = ln & 15, ko = (ln >> 4) * 8;
  bf16x8 qf[2];
  #pragma unroll
  for (int kw = 0; kw < 2; ++kw)
    qf[kw] = *(const bf16x8*)&Qs[swz(w * 16 + rsel, ko + 32 * kw)];

  f32x4 acc2[4] = {};          // O[q=(ln>>4)*4+i][d=16n+rsel]
  float m = -1e30f, l = 0.f;   // per-lane state for q-row = rsel (scores pre-scaled)

  // preload KV tile 0 (K: 1024 granules; V^T: 64 rows x 16 granules) 2/thread each
  uint4 kg[2], vg[2];
  #pragma unroll
  for (int i = 0; i < 2; ++i) {
    int g = t + i * 512;
    kg[i] = *(const uint4*)&Kb[(size_t)(g >> 3) * DK + (g & 7) * 8];
    vg[i] = *(const uint4*)&Vb[(size_t)(g >> 4) * SQ + (g & 15) * 8];
  }

  for (int c0 = 0; c0 < SQ; c0 += 128) {
    __syncthreads();  // previous tile's Ks/Vt reads done
    #pragma unroll
    for (int i = 0; i < 2; ++i) {
      int g = t + i * 512;
      int r = g >> 3, cg = g & 7;
      *(uint4*)&Ks[r * 64 + (((cg ^ fswz(r)) & 7) << 3)] = kg[i];
      int d = g >> 4, c = g & 15;
      *(uint4*)&Vt[d * 128 + vslot(d, c) * 8] = vg[i];
    }
    __syncthreads();

    if (c0 + 128 < SQ) {  // prefetch next KV tile under compute
      #pragma unroll
      for (int i = 0; i < 2; ++i) {
        int g = t + i * 512;
        kg[i] = *(const uint4*)&Kb[(size_t)(c0 + 128 + (g >> 3)) * DK + (g & 7) * 8];
        vg[i] = *(const uint4*)&Vb[(size_t)(g >> 4) * SQ + c0 + 128 + (g & 15) * 8];
      }
    }

    #pragma unroll
    for (int it = 0; it < 2; ++it) {
      // QK^T (swapped): lane holds S[kv=it*64+fr*16+(ln>>4)*4+i][q=rsel]
      f32x4 s[4] = {};
      __builtin_amdgcn_s_setprio(1);
      #pragma unroll
      for (int kw = 0; kw < 2; ++kw)
        #pragma unroll
        for (int fr = 0; fr < 4; ++fr) {
          bf16x8 kf = *(const bf16x8*)&Ks[swz(it * 64 + fr * 16 + rsel, ko + 32 * kw)];
          s[fr] = __builtin_amdgcn_mfma_f32_16x16x32_bf16(kf, qf[kw], s[fr], 0, 0, 0);
        }
      __builtin_amdgcn_s_setprio(0);

      // row max (tree), cross-replica combine
      float t0 = fmaxf(fmaxf(s[0][0], s[0][1]), fmaxf(s[0][2], s[0][3]));
      float t1 = fmaxf(fmaxf(s[1][0], s[1][1]), fmaxf(s[1][2], s[1][3]));
      float t2 = fmaxf(fmaxf(s[2][0], s[2][1]), fmaxf(s[2][2], s[2][3]));
      float t3 = fmaxf(fmaxf(s[3][0], s[3][1]), fmaxf(s[3][2], s[3][3]));
      float tm = fmaxf(fmaxf(t0, t1), fmaxf(t2, t3));
      tm = fmaxf(tm, __shfl_xor(tm, 16));
      tm = fmaxf(tm, __shfl_xor(tm, 32));

      // defer-max: rescale only when some row's max grew by > 8
      if (__any((tm - m) > 8.f)) {
        const float mnew = fmaxf(m, tm);
        const float corr = __expf(m - mnew);
        float ci[4];
        #pragma unroll
        for (int i = 0; i < 4; ++i) ci[i] = __shfl(corr, (ln >> 4) * 4 + i);
        #pragma unroll
        for (int n = 0; n < 4; ++n)
          #pragma unroll
          for (int i = 0; i < 4; ++i) acc2[n][i] *= ci[i];
        l *= corr;
        m = mnew;
      }

      // exp in place (s becomes P)
      #pragma unroll
      for (int fr = 0; fr < 4; ++fr)
        #pragma unroll
        for (int i = 0; i < 4; ++i)
          s[fr][i] = __expf(s[fr][i] - m);
      float a0 = (s[0][0] + s[0][1]) + (s[0][2] + s[0][3]);
      float a1 = (s[1][0] + s[1][1]) + (s[1][2] + s[1][3]);
      float a2 = (s[2][0] + s[2][1]) + (s[2][2] + s[2][3]);
      float a3 = (s[3][0] + s[3][1]) + (s[3][2] + s[3][3]);
      float ps = (a0 + a1) + (a2 + a3);
      ps += __shfl_xor(ps, 16);
      ps += __shfl_xor(ps, 32);
      l += ps;

      // pack P (v_cvt_pk_bf16_f32) and write to this wave's LDS region
      #pragma unroll
      for (int fr = 0; fr < 4; ++fr) {
        unsigned r01, r23;
        asm("v_cvt_pk_bf16_f32 %0, %1, %2" : "=v"(r01) : "v"(s[fr][0]), "v"(s[fr][1]));
        asm("v_cvt_pk_bf16_f32 %0, %1, %2" : "=v"(r23) : "v"(s[fr][2]), "v"(s[fr][3]));
        uint2 pv = {r01, r23};
        const int kk0 = (ln >> 4) * 4 + fr * 16;
        *(uint2*)&Pl[w * 1024 + swz(rsel, kk0)] = pv;
      }

      // PV: A = P rows (wave-local), B = Vt rows (kv window it*64..)
      __builtin_amdgcn_s_setprio(1);
      #pragma unroll
      for (int kw = 0; kw < 2; ++kw) {
        bf16x8 pf = *(const bf16x8*)&Pl[w * 1024 + swz(rsel, ko + 32 * kw)];
        #pragma unroll
        for (int n = 0; n < 4; ++n) {
          const int d = n * 16 + rsel;
          const int gx = it * 8 + (ln >> 4) + 4 * kw;
          bf16x8 vf = *(const bf16x8*)&Vt[d * 128 + vslot(d, gx) * 8];
          acc2[n] = __builtin_amdgcn_mfma_f32_16x16x32_bf16(pf, vf, acc2[n], 0, 0, 0);
        }
      }
      __builtin_amdgcn_s_setprio(0);
    }
  }

  // epilogue: divide by l and store bf16 ctx [B][S][DM]
  const float rl = 1.0f / l;
  float ri[4];
  #pragma unroll
  for (int i = 0; i < 4; ++i) ri[i] = __shfl(rl, (ln >> 4) * 4 + i);
  const int b = bh >> 4, h = bh & 15;
  #pragma unroll
  for (int n = 0; n < 4; ++n)
    #pragma unroll
    for (int i = 0; i < 4; ++i) {
      const int srow = q0 + w * 16 + (ln >> 4) * 4 + i;
      ctx[((size_t)(b * SQ + srow)) * DM + h * 64 + n * 16 + rsel] =
          f2bf(acc2[n][i] * ri[i]);
    }
}

extern "C" void kernel_launch(void* const* d_in, const int* in_sizes, int n_in,
                              void* d_out, int out_size, void* d_ws, size_t ws_size,
                              hipStream_t stream) {
  const float* x  = (const float*)d_in[0];
  const float* Wq = (const float*)d_in[1];
  const float* bq = (const float*)d_in[2];
  const float* Wk = (const float*)d_in[3];
  const float* bk = (const float*)d_in[4];
  const float* Wv = (const float*)d_in[5];
  const float* bv = (const float*)d_in[6];
  const float* Wo = (const float*)d_in[7];
  const float* bo = (const float*)d_in[8];
  float* out = (float*)d_out;

  unsigned short* xb    = (unsigned short*)d_ws;             // [MR,DM] bf16, 8MB
  unsigned short* Wt3   = xb   + (size_t)MR * DM;            // [3072,1024] bf16, 6MB
  unsigned short* Wto   = Wt3  + (size_t)3 * DM * DM;        // [1024,1024] bf16, 2MB
  unsigned short* QKVb  = Wto  + (size_t)DM * DM;            // 3x [B,H,S,DK] bf16, 24MB
  unsigned short* Vtb   = QKVb + (size_t)3 * MR * DM;        // [B,H,DK,S] bf16, 8MB
  unsigned short* ctxb  = Vtb  + (size_t)MR * DM;            // [B,S,DM] bf16, 8MB
  // total ~56 MB

  cast_kernel<<<(MR * DM / 8 + 255) / 256, 256, 0, stream>>>(x, xb, MR * DM / 8);
  transpose_cast_all<<<dim3(DM / 32, DM / 32, 4), 256, 0, stream>>>(
      Wq, Wk, Wv, Wo, Wt3, Wto);

  qkv_gemm<<<dim3(3 * DM / 128, MR / 128), 256, 0, stream>>>(
      xb, Wt3, bq, bk, bv, QKVb);
  transpose_v<<<dim3(SQ / 64, BB * NH), 256, 0, stream>>>(
      QKVb + (size_t)2 * MR * DM, Vtb);

  attn_mfma<<<dim3(SQ / 128, BB * NH), 512, 0, stream>>>(
      QKVb, QKVb + (size_t)MR * DM, Vtb, ctxb);

  mfma_gemm_out<<<dim3(DM / 128, MR / 128), 256, 0, stream>>>(ctxb, Wto, bo, out);
}